// Round 1
// baseline (505.753 us; speedup 1.0000x reference)
//
#include <hip/hip_runtime.h>
#include <hip/hip_bf16.h>

constexpr int MTOK = 1024;   // B*S
constexpr int HDIM = 2048;
constexpr int IDIM = 2048;
constexpr int NEXP = 16;
constexpr int TOPK = 4;
constexpr int NA   = MTOK * TOPK;   // 4096 assignments

#define ALPHA_C 1.702f
#define LIMIT_C 7.0f
#define RMS_EPS 1e-5f

using short8   = __attribute__((ext_vector_type(8))) short;
using ushort4v = __attribute__((ext_vector_type(4))) unsigned short;
using f32x4    = __attribute__((ext_vector_type(4))) float;

__device__ __forceinline__ unsigned short f2bf(float f) {
    unsigned u = __builtin_bit_cast(unsigned, f);
    u += 0x7fffu + ((u >> 16) & 1u);     // round-to-nearest-even
    return (unsigned short)(u >> 16);
}

// ---------------- out = x ----------------
__global__ void k_copy(const float* __restrict__ x, float* __restrict__ out, int n4) {
    int i = blockIdx.x * blockDim.x + threadIdx.x;
    int stride = gridDim.x * blockDim.x;
    const float4* xs = (const float4*)x;
    float4* os = (float4*)out;
    for (; i < n4; i += stride) os[i] = xs[i];
}

// ---------------- RMSNorm + router + top-k ----------------
__global__ __launch_bounds__(256) void k_router(
    const float* __restrict__ x, const float* __restrict__ norm_w,
    const float* __restrict__ gate_w, const float* __restrict__ gate_b,
    unsigned short* __restrict__ t_bf,
    int* __restrict__ counts, int* __restrict__ idx_of,
    int* __restrict__ slot_of, float* __restrict__ gate_mk)
{
    __shared__ float t_lds[HDIM];
    __shared__ float red[4];
    __shared__ float logits[NEXP];

    const int m   = blockIdx.x;
    const int tid = threadIdx.x;
    const float* xr = x + (size_t)m * HDIM;

    float4 v0 = ((const float4*)xr)[tid * 2];
    float4 v1 = ((const float4*)xr)[tid * 2 + 1];
    float ss = v0.x*v0.x + v0.y*v0.y + v0.z*v0.z + v0.w*v0.w
             + v1.x*v1.x + v1.y*v1.y + v1.z*v1.z + v1.w*v1.w;
    // wave reduce (64 lanes)
    #pragma unroll
    for (int off = 32; off > 0; off >>= 1) ss += __shfl_down(ss, off);
    if ((tid & 63) == 0) red[tid >> 6] = ss;
    __syncthreads();
    float tot = red[0] + red[1] + red[2] + red[3];
    float scale = rsqrtf(tot / (float)HDIM + RMS_EPS);

    float4 n0 = ((const float4*)norm_w)[tid * 2];
    float4 n1 = ((const float4*)norm_w)[tid * 2 + 1];
    float t[8];
    t[0]=v0.x*scale*n0.x; t[1]=v0.y*scale*n0.y; t[2]=v0.z*scale*n0.z; t[3]=v0.w*scale*n0.w;
    t[4]=v1.x*scale*n1.x; t[5]=v1.y*scale*n1.y; t[6]=v1.z*scale*n1.z; t[7]=v1.w*scale*n1.w;
    short8 pk;
    #pragma unroll
    for (int j = 0; j < 8; ++j) {
        t_lds[tid * 8 + j] = t[j];
        pk[j] = (short)f2bf(t[j]);
    }
    *(short8*)(t_bf + (size_t)m * HDIM + tid * 8) = pk;
    __syncthreads();

    // 16 threads per expert: e = tid>>4, j = tid&15
    const int e = tid >> 4, j = tid & 15;
    const float* gw = gate_w + (size_t)e * HDIM;
    float part = 0.f;
    for (int h = j; h < HDIM; h += 16) part += t_lds[h] * gw[h];
    #pragma unroll
    for (int off = 8; off > 0; off >>= 1) part += __shfl_xor(part, off);
    if (j == 0) logits[e] = part + gate_b[e];
    __syncthreads();

    if (tid == 0) {
        float lv[NEXP];
        #pragma unroll
        for (int q = 0; q < NEXP; ++q) lv[q] = logits[q];
        int   sel[TOPK];
        float sv[TOPK];
        #pragma unroll
        for (int k = 0; k < TOPK; ++k) {
            float best = -1e30f; int bi = 0;
            for (int q = 0; q < NEXP; ++q)
                if (lv[q] > best) { best = lv[q]; bi = q; }
            sel[k] = bi; sv[k] = best; lv[bi] = -1e30f;
        }
        float mx = sv[0], s = 0.f, g[TOPK];
        #pragma unroll
        for (int k = 0; k < TOPK; ++k) { g[k] = __expf(sv[k] - mx); s += g[k]; }
        float inv = 1.f / s;
        #pragma unroll
        for (int k = 0; k < TOPK; ++k) {
            int a = m * TOPK + k;
            int slot = atomicAdd(&counts[sel[k]], 1);
            idx_of[a]  = sel[k];
            slot_of[a] = slot;
            gate_mk[a] = g[k] * inv;
        }
    }
}

// ---------------- exclusive scan of counts ----------------
__global__ void k_offsets(const int* __restrict__ counts, int* __restrict__ offsets) {
    if (threadIdx.x == 0) {
        int s = 0;
        for (int e = 0; e < NEXP; ++e) { offsets[e] = s; s += counts[e]; }
        offsets[NEXP] = s;
    }
}

// ---------------- scatter tokens into compact per-expert rows ----------------
__global__ void k_remap(const int* __restrict__ idx_of, const int* __restrict__ slot_of,
                        const float* __restrict__ gate_mk, const int* __restrict__ offsets,
                        int* __restrict__ token_of, float* __restrict__ gate_row)
{
    int a = blockIdx.x * blockDim.x + threadIdx.x;
    if (a >= NA) return;
    int e = idx_of[a];
    int r = offsets[e] + slot_of[a];
    token_of[r] = a >> 2;
    gate_row[r] = gate_mk[a];
}

// ---------------- GEMM1 + bias + clamped SwiGLU -> act (bf16) ----------------
// C[r, o] = sum_h t[r,h] * w1[e,o,h];  block: 128 rows x 32 i-values (64 o-cols,
// arranged a-half [j<32]->o=2i, b-half [j>=32]->o=2i+1 so pairs share a lane).
__global__ __launch_bounds__(512) void k_gemm1(
    const unsigned short* __restrict__ t_bf,
    const float* __restrict__ w1, const float* __restrict__ b1,
    const int* __restrict__ counts, const int* __restrict__ offsets,
    const int* __restrict__ token_of,
    unsigned short* __restrict__ act)
{
    constexpr int BM = 128, BK = 32, LD = 80;  // 80B row stride: 2-way LDS conflict (free)
    __shared__ unsigned char lA[BM * LD];      // 10240 B
    __shared__ unsigned char lB[64 * LD];      // 5120 B

    const int e  = blockIdx.z;
    const int ne = counts[e];
    const int brow = blockIdx.y * BM;
    if (brow >= ne) return;
    const int roff = offsets[e];
    const int i0 = blockIdx.x * 32;
    const int tid = threadIdx.x;

    // A staging: row = tid>>2 (0..127), 16B chunk = tid&3
    const int ar = tid >> 2, ap = tid & 3;
    const unsigned short* asrc = nullptr;
    if (brow + ar < ne) asrc = t_bf + (size_t)token_of[roff + brow + ar] * HDIM;
    // B staging: row j = tid>>3 (0..63), 4-float chunk = tid&7
    const int bj = tid >> 3, bp = tid & 7;
    const int o  = (bj < 32) ? (2 * (i0 + bj)) : (2 * (i0 + bj - 32) + 1);
    const float* bsrc = w1 + ((size_t)e * (2 * IDIM) + o) * HDIM;

    const int wv = tid >> 6, ln = tid & 63;
    const int lr = ln & 15, lk = ln >> 4;

    f32x4 acc[4] = {};
    for (int k0 = 0; k0 < HDIM; k0 += BK) {
        __syncthreads();
        short8 av = {};
        if (asrc) av = *(const short8*)(asrc + k0 + ap * 8);
        *(short8*)(lA + ar * LD + ap * 16) = av;
        float4 bv = *(const float4*)(bsrc + k0 + bp * 4);
        ushort4v bw = { f2bf(bv.x), f2bf(bv.y), f2bf(bv.z), f2bf(bv.w) };
        *(ushort4v*)(lB + bj * LD + bp * 8) = bw;
        __syncthreads();

        short8 afrag = *(const short8*)(lA + (wv * 16 + lr) * LD + lk * 16);
        #pragma unroll
        for (int n = 0; n < 4; ++n) {
            short8 bfrag = *(const short8*)(lB + (n * 16 + lr) * LD + lk * 16);
            acc[n] = __builtin_amdgcn_mfma_f32_16x16x32_bf16(afrag, bfrag, acc[n], 0, 0, 0);
        }
    }

    const int mbase = wv * 16 + lk * 4;
    #pragma unroll
    for (int n = 0; n < 2; ++n) {
        const int i = i0 + n * 16 + lr;
        const float ba = b1[(size_t)e * (2 * IDIM) + 2 * i];
        const float bb = b1[(size_t)e * (2 * IDIM) + 2 * i + 1];
        #pragma unroll
        for (int r = 0; r < 4; ++r) {
            const int rg = brow + mbase + r;
            if (rg < ne) {
                float ha = acc[n][r] + ba;
                float hb = acc[n + 2][r] + bb;
                float a = fminf(ha, LIMIT_C);
                float b = fminf(fmaxf(hb, -LIMIT_C), LIMIT_C);
                float s = 1.f / (1.f + __expf(-ALPHA_C * a));
                act[(size_t)(roff + rg) * IDIM + i] = f2bf(a * s * (b + 1.f));
            }
        }
    }
}

// ---------------- GEMM2 + bias, gate-scale, atomic combine ----------------
// C[r, d] = sum_i act[r,i] * w2[e,d,i];  out[tok,d] += gate * (C + b2[e,d])
__global__ __launch_bounds__(512) void k_gemm2(
    const unsigned short* __restrict__ act,
    const float* __restrict__ w2, const float* __restrict__ b2,
    const int* __restrict__ counts, const int* __restrict__ offsets,
    const int* __restrict__ token_of, const float* __restrict__ gate_row,
    float* __restrict__ out)
{
    constexpr int BM = 128, BK = 32, LD = 80;
    __shared__ unsigned char lA[BM * LD];
    __shared__ unsigned char lB[64 * LD];

    const int e  = blockIdx.z;
    const int ne = counts[e];
    const int brow = blockIdx.y * BM;
    if (brow >= ne) return;
    const int roff = offsets[e];
    const int d0 = blockIdx.x * 64;
    const int tid = threadIdx.x;

    const int ar = tid >> 2, ap = tid & 3;
    const unsigned short* asrc = nullptr;
    if (brow + ar < ne) asrc = act + (size_t)(roff + brow + ar) * IDIM;
    const int bj = tid >> 3, bp = tid & 7;
    const float* bsrc = w2 + ((size_t)e * HDIM + d0 + bj) * IDIM;

    const int wv = tid >> 6, ln = tid & 63;
    const int lr = ln & 15, lk = ln >> 4;

    f32x4 acc[4] = {};
    for (int k0 = 0; k0 < IDIM; k0 += BK) {
        __syncthreads();
        short8 av = {};
        if (asrc) av = *(const short8*)(asrc + k0 + ap * 8);
        *(short8*)(lA + ar * LD + ap * 16) = av;
        float4 bv = *(const float4*)(bsrc + k0 + bp * 4);
        ushort4v bw = { f2bf(bv.x), f2bf(bv.y), f2bf(bv.z), f2bf(bv.w) };
        *(ushort4v*)(lB + bj * LD + bp * 8) = bw;
        __syncthreads();

        short8 afrag = *(const short8*)(lA + (wv * 16 + lr) * LD + lk * 16);
        #pragma unroll
        for (int n = 0; n < 4; ++n) {
            short8 bfrag = *(const short8*)(lB + (n * 16 + lr) * LD + lk * 16);
            acc[n] = __builtin_amdgcn_mfma_f32_16x16x32_bf16(afrag, bfrag, acc[n], 0, 0, 0);
        }
    }

    const int mbase = wv * 16 + lk * 4;
    #pragma unroll
    for (int r = 0; r < 4; ++r) {
        const int rg = brow + mbase + r;
        if (rg < ne) {
            const int tok = token_of[roff + rg];
            const float g = gate_row[roff + rg];
            float* orow = out + (size_t)tok * HDIM;
            #pragma unroll
            for (int n = 0; n < 4; ++n) {
                const int d = d0 + n * 16 + lr;
                atomicAdd(orow + d, g * (acc[n][r] + b2[(size_t)e * HDIM + d]));
            }
        }
    }
}

extern "C" void kernel_launch(void* const* d_in, const int* in_sizes, int n_in,
                              void* d_out, int out_size, void* d_ws, size_t ws_size,
                              hipStream_t stream) {
    const float* x      = (const float*)d_in[0];
    const float* norm_w = (const float*)d_in[1];
    const float* gate_w = (const float*)d_in[2];
    const float* gate_b = (const float*)d_in[3];
    const float* w1     = (const float*)d_in[4];
    const float* b1     = (const float*)d_in[5];
    const float* w2     = (const float*)d_in[6];
    const float* b2     = (const float*)d_in[7];
    float* out = (float*)d_out;

    char* ws = (char*)d_ws;
    size_t off = 0;
    unsigned short* t_bf = (unsigned short*)(ws + off); off += (size_t)MTOK * HDIM * 2;  // 4 MB
    unsigned short* actb = (unsigned short*)(ws + off); off += (size_t)NA * IDIM * 2;    // 16.8 MB
    int*   counts   = (int*)(ws + off);   off += 256;
    int*   offsets  = (int*)(ws + off);   off += 256;
    int*   idx_of   = (int*)(ws + off);   off += (size_t)NA * 4;
    int*   slot_of  = (int*)(ws + off);   off += (size_t)NA * 4;
    float* gate_mk  = (float*)(ws + off); off += (size_t)NA * 4;
    int*   token_of = (int*)(ws + off);   off += (size_t)NA * 4;
    float* gate_row = (float*)(ws + off); off += (size_t)NA * 4;

    hipMemsetAsync(counts, 0, 256, stream);
    k_copy<<<1024, 256, 0, stream>>>(x, out, MTOK * HDIM / 4);
    k_router<<<MTOK, 256, 0, stream>>>(x, norm_w, gate_w, gate_b, t_bf,
                                       counts, idx_of, slot_of, gate_mk);
    k_offsets<<<1, 64, 0, stream>>>(counts, offsets);
    k_remap<<<NA / 256, 256, 0, stream>>>(idx_of, slot_of, gate_mk, offsets,
                                          token_of, gate_row);
    k_gemm1<<<dim3(IDIM / 32, MTOK / 128, NEXP), 512, 0, stream>>>(
        t_bf, w1, b1, counts, offsets, token_of, actb);
    k_gemm2<<<dim3(HDIM / 64, MTOK / 128, NEXP), 512, 0, stream>>>(
        actb, w2, b2, counts, offsets, token_of, gate_row, out);
}